// Round 6
// baseline (151.655 us; speedup 1.0000x reference)
//
#include <hip/hip_runtime.h>

// WaveletLayer on [4096,4096] fp32:
//   out = diag_s * DWT3( diag_g * (DWT3(diag_b * x))[perm] )
// Haar DWT3 packet layout: [cA3(512) | cD3(512) | cD2(1024) | cD1(2048)].
//
// History:
//  v1: 16-cols/thread, reg tables, dbuf LDS, R=4, 256-thr blocks. 44 us.
//  v2: LDS-only barrier + prefetch -> regressed.
//  v3: launch_bounds(256,8) + reg tables -> spill, 90 us.
//  v4: natural regs -> VGPR=68, 44 us.
//  v5: coalesced chunk layout -> ~41 us.
//  v6: tables per-use, VGPR=28, occupancy 61% -> STILL 42.9 us. VALUBusy
//      12% at 61% occupancy => all waves stall simultaneously: barrier
//      LOCKSTEP. Identical blocks hit load-wait / barrier / gather-wait in
//      phase, so resident blocks can't cover each other's latency.
//  v7 (this round): eliminate the barrier entirely. One WAVE per block
//      (NT=64): the DS pipe is in-order per wave, so scatter->gather in the
//      wave-private 16 KB LDS buffer needs NO s_barrier and NO vmcnt drain.
//      Every wave free-runs; compiler can hoist table loads and next-row
//      x-loads without limit (2 waves/SIMD -> 256-VGPR budget). grid=2048,
//      R=2 rows/block -> 8 blocks/CU (LDS 128/160 KB).

#define D   4096
#define NT  64             // ONE wave: 16 chunks x 4 columns per lane
#define R   2              // rows per block -> grid 2048 = 8 blocks/CU

#define C_INV_SQRT2 0.70710678118654752440f

typedef float vf2 __attribute__((ext_vector_type(2)));
typedef float vf4 __attribute__((ext_vector_type(4)));

// One Haar chunk: 4 contiguous columns -> d1 pair, d2, and level-3 value
// (even lane: cA3, odd lane: cD3) via cross-lane pairing of a2.
static __device__ __forceinline__ void haar_chunk(
    float v0, float v1, float v2, float v3, int odd,
    float& d1a, float& d1b, float& d2v, float& l3)
{
    float a10 = (v0 + v1) * C_INV_SQRT2;
    d1a       = (v0 - v1) * C_INV_SQRT2;
    float a11 = (v2 + v3) * C_INV_SQRT2;
    d1b       = (v2 - v3) * C_INV_SQRT2;
    float a2  = (a10 + a11) * C_INV_SQRT2;
    d2v       = (a10 - a11) * C_INV_SQRT2;
    float a2p = __shfl_xor(a2, 1);              // neighbor's a2 (lane t^1)
    // even lane holds a2[2m], partner a2[2m+1]:  a3 = (a2 + a2p)*c
    // odd  lane holds a2[2m+1], partner a2[2m]:  d3 = (a2p - a2)*c
    l3 = (odd ? (a2p - a2) : (a2 + a2p)) * C_INV_SQRT2;
}

__global__ __launch_bounds__(NT) void wavelet_wave_kernel(
    const float* __restrict__ x,
    const float* __restrict__ diag_s,
    const float* __restrict__ diag_g,
    const float* __restrict__ diag_b,
    const int*   __restrict__ perm,
    float*       __restrict__ out)
{
    __shared__ float buf[D];          // wave-private packet buffer: 16 KB

    const int t   = threadIdx.x;      // lane 0..63
    const int s_  = t >> 1;           // lane-pair index
    const int odd = t & 1;
    const size_t row0 = (size_t)blockIdx.x * R;

    const vf4*  b4 = (const vf4*)diag_b;
    const vf4*  g4 = (const vf4*)diag_g;
    const int4* p4 = (const int4*)perm;
    const vf2*  s2 = (const vf2*)diag_s;

    for (int r = 0; r < R; ++r) {
        const vf4* x4 = (const vf4*)(x + (row0 + r) * (size_t)D);

        // ---- phase A: load (coalesced 1 KB/instr), DWT #1, scatter ----
        // chunk k covers columns 256k + 4t .. +3
        #pragma unroll
        for (int k = 0; k < 16; ++k) {
            vf4 xv = x4[64 * k + t];                   // HBM
            vf4 bv = b4[64 * k + t];                   // L2-hot
            float d1a, d1b, d2v, l3;
            haar_chunk(xv.x * bv.x, xv.y * bv.y,
                       xv.z * bv.z, xv.w * bv.w, odd,
                       d1a, d1b, d2v, l3);
            vf2 dp; dp.x = d1a; dp.y = d1b;
            *(vf2*)&buf[2048 + 128 * k + 2 * t] = dp;  // cD1 pair (stride-8B, conflict-free)
            buf[1024 + 64 * k + t] = d2v;              // cD2 (stride-1)
            buf[(odd ? 512 : 0) + 32 * k + s_] = l3;   // cA3|cD3 (2 lanes/bank = free)
        }

        // NO barrier: single-wave block. DS ops are in-order per wave, so
        // the gather below reads the scattered data; the compiler's
        // lgkmcnt handles register availability. Global loads/stores are
        // free to be hoisted/pipelined across this point.

        // ---- phase B: gather * diag_g, DWT #2, * diag_s, NT store ----
        float* orow = out + (row0 + r) * (size_t)D;
        #pragma unroll
        for (int k = 0; k < 16; ++k) {
            int4  pv  = p4[64 * k + t];                // L2-hot tables
            vf4   gv  = g4[64 * k + t];
            vf2   s1  = s2[1024 + 64 * k + t];         // cD1 scale pair
            float sv2 = diag_s[1024 + 64 * k + t];     // cD2 scale
            float sv3 = diag_s[(odd ? 512 : 0) + 32 * k + s_];

            float w0 = buf[pv.x] * gv.x;
            float w1 = buf[pv.y] * gv.y;
            float w2 = buf[pv.z] * gv.z;
            float w3 = buf[pv.w] * gv.w;
            float e1a, e1b, e2v, f3;
            haar_chunk(w0, w1, w2, w3, odd, e1a, e1b, e2v, f3);

            vf2 ep; ep.x = e1a * s1.x; ep.y = e1b * s1.y;
            __builtin_nontemporal_store(ep, &((vf2*)orow)[1024 + 64 * k + t]);
            __builtin_nontemporal_store(e2v * sv2, &orow[1024 + 64 * k + t]);
            __builtin_nontemporal_store(f3 * sv3,
                                        &orow[(odd ? 512 : 0) + 32 * k + s_]);
        }
        // Cross-row safety, also barrier-free: row r+1's ds_writes are
        // issued after row r's ds_reads in program order; the in-order DS
        // pipe preserves read-before-overwrite within the wave.
    }
}

extern "C" void kernel_launch(void* const* d_in, const int* in_sizes, int n_in,
                              void* d_out, int out_size, void* d_ws, size_t ws_size,
                              hipStream_t stream) {
    // setup_inputs() order: x, diag_s, diag_g, diag_b, dec_lo, dec_hi, perm, scales
    const float* x      = (const float*)d_in[0];
    const float* diag_s = (const float*)d_in[1];
    const float* diag_g = (const float*)d_in[2];
    const float* diag_b = (const float*)d_in[3];
    const int* perm     = (const int*)d_in[6];
    float* out          = (float*)d_out;

    wavelet_wave_kernel<<<4096 / R, NT, 0, stream>>>(x, diag_s, diag_g, diag_b,
                                                     perm, out);
}

// Round 7
// 133.084 us; speedup vs baseline: 1.1395x; 1.1395x over previous
//
#include <hip/hip_runtime.h>

// WaveletLayer on [4096,4096] fp32:
//   out = diag_s * DWT3( diag_g * (DWT3(diag_b * x))[perm] )
// Haar DWT3 packet layout: [cA3(512) | cD3(512) | cD2(1024) | cD1(2048)].
//
// History:
//  v1: 16-cols/thread, reg tables, dbuf LDS, R=4, 256-thr blocks. 44 us.
//  v2: LDS-only barrier + prefetch -> regressed.
//  v3: launch_bounds(256,8) + reg tables -> spill, 90 us.
//  v4: natural regs -> VGPR=68, 44 us.
//  v5: coalesced chunk layout -> ~41 us.
//  v6: per-use tables, VGPR=28, occupancy 61%, traffic minimal (33 MB
//      fetch / 64 MB write) -> STILL 42.9 us. Occupancy, coalescing,
//      barrier structure all falsified as limiters.
//  v7: single-wave blocks, no barrier -> 60-76 us (VGPR=172, too few
//      waves; rows-in-flight unchanged). Dead end.
//  v8 (this round): SINGLE-VARIABLE probe of the one never-varied
//      component: the store path. v1-v7 all used nontemporal stores
//      (streaming/no-allocate) -- plausibly bypassing L2 write-combining,
//      pacing HBM writes per-wave-burst and forcing read/write bus
//      turnarounds. fillBuffer (plain cached stores) streams 6.3 TB/s;
//      our kernel is stuck at 2.4. v8 = v6 with PLAIN stores, everything
//      else identical.

#define D   4096
#define NT  256            // 4 chunks x 4 columns per thread

#define C_INV_SQRT2 0.70710678118654752440f

typedef float vf2 __attribute__((ext_vector_type(2)));
typedef float vf4 __attribute__((ext_vector_type(4)));

// One Haar chunk: 4 contiguous columns -> d1 pair, d2, and level-3 value
// (even lane: cA3, odd lane: cD3) via cross-lane pairing of a2.
static __device__ __forceinline__ void haar_chunk(
    float v0, float v1, float v2, float v3, int odd,
    float& d1a, float& d1b, float& d2v, float& l3)
{
    float a10 = (v0 + v1) * C_INV_SQRT2;
    d1a       = (v0 - v1) * C_INV_SQRT2;
    float a11 = (v2 + v3) * C_INV_SQRT2;
    d1b       = (v2 - v3) * C_INV_SQRT2;
    float a2  = (a10 + a11) * C_INV_SQRT2;
    d2v       = (a10 - a11) * C_INV_SQRT2;
    float a2p = __shfl_xor(a2, 1);              // neighbor's a2 (lane t^1)
    // even lane holds a2[2m], partner a2[2m+1]:  a3 = (a2 + a2p)*c
    // odd  lane holds a2[2m+1], partner a2[2m]:  d3 = (a2p - a2)*c
    l3 = (odd ? (a2p - a2) : (a2 + a2p)) * C_INV_SQRT2;
}

__global__ __launch_bounds__(NT, 8) void wavelet_rows_kernel(
    const float* __restrict__ x,
    const float* __restrict__ diag_s,
    const float* __restrict__ diag_g,
    const float* __restrict__ diag_b,
    const int*   __restrict__ perm,
    float*       __restrict__ out)
{
    __shared__ float buf[D];          // single packet buffer: 16 KB/block

    const int t   = threadIdx.x;
    const int s   = t >> 1;           // lane-pair index
    const int odd = t & 1;
    const size_t row = (size_t)blockIdx.x;

    const vf4*  b4 = (const vf4*)diag_b;
    const vf4*  g4 = (const vf4*)diag_g;
    const int4* p4 = (const int4*)perm;
    const vf2*  s2 = (const vf2*)diag_s;

    // ---- phase A: load row (coalesced), DWT #1, scatter packet to LDS ----
    const vf4* x4 = (const vf4*)(x + row * (size_t)D);
    #pragma unroll
    for (int k = 0; k < 4; ++k) {
        vf4 xv = x4[256 * k + t];                      // HBM, 16B/lane coalesced
        vf4 bv = b4[256 * k + t];                      // L2-hot
        float d1a, d1b, d2v, l3;
        haar_chunk(xv.x * bv.x, xv.y * bv.y,
                   xv.z * bv.z, xv.w * bv.w, odd,
                   d1a, d1b, d2v, l3);
        vf2 dp; dp.x = d1a; dp.y = d1b;
        *(vf2*)&buf[2048 + 512 * k + 2 * t] = dp;      // cD1 pair
        buf[1024 + 256 * k + t] = d2v;                 // cD2
        buf[(odd ? 512 : 0) + 128 * k + s] = l3;       // cA3 | cD3
    }

    // prefetch permutation indices for phase B: the L2 latency of these
    // loads overlaps the barrier wait (they're the gather critical path).
    int4 pidx[4];
    #pragma unroll
    for (int k = 0; k < 4; ++k) pidx[k] = p4[256 * k + t];

    __syncthreads();

    // ---- phase B: gather * diag_g, DWT #2, * diag_s, PLAIN store ----
    float* orow = out + row * (size_t)D;
    #pragma unroll
    for (int k = 0; k < 4; ++k) {
        // per-chunk table loads (L2-hot); latency hides under the ds_reads
        vf4  gv  = g4[256 * k + t];
        vf2  s1  = s2[1024 + 256 * k + t];             // cD1 scale pair
        float sv2 = diag_s[1024 + 256 * k + t];        // cD2 scale
        float sv3 = diag_s[(odd ? 512 : 0) + 128 * k + s];  // cA3|cD3 scale

        float w0 = buf[pidx[k].x] * gv.x;
        float w1 = buf[pidx[k].y] * gv.y;
        float w2 = buf[pidx[k].z] * gv.z;
        float w3 = buf[pidx[k].w] * gv.w;
        float e1a, e1b, e2v, f3;
        haar_chunk(w0, w1, w2, w3, odd, e1a, e1b, e2v, f3);

        // v8: plain cached stores (write-back L2 absorbs and paces the
        // HBM writes; full-line combining decoupled from wave issue).
        vf2 ep; ep.x = e1a * s1.x; ep.y = e1b * s1.y;
        ((vf2*)orow)[1024 + 256 * k + t] = ep;
        orow[1024 + 256 * k + t] = e2v * sv2;
        orow[(odd ? 512 : 0) + 128 * k + s] = f3 * sv3;
    }
}

extern "C" void kernel_launch(void* const* d_in, const int* in_sizes, int n_in,
                              void* d_out, int out_size, void* d_ws, size_t ws_size,
                              hipStream_t stream) {
    // setup_inputs() order: x, diag_s, diag_g, diag_b, dec_lo, dec_hi, perm, scales
    const float* x      = (const float*)d_in[0];
    const float* diag_s = (const float*)d_in[1];
    const float* diag_g = (const float*)d_in[2];
    const float* diag_b = (const float*)d_in[3];
    const int* perm     = (const int*)d_in[6];
    float* out          = (float*)d_out;

    wavelet_rows_kernel<<<4096, NT, 0, stream>>>(x, diag_s, diag_g, diag_b, perm, out);
}

// Round 8
// 128.903 us; speedup vs baseline: 1.1765x; 1.0324x over previous
//
#include <hip/hip_runtime.h>

// WaveletLayer on [4096,4096] fp32:
//   out = diag_s * DWT3( diag_g * (DWT3(diag_b * x))[perm] )
// Haar DWT3 packet layout: [cA3(512) | cD3(512) | cD2(1024) | cD1(2048)].
//
// History:
//  v1: 16-cols/thread, reg tables, dbuf LDS, R=4. 44 us.
//  v2: LDS-only barrier + reg prefetch -> regressed.
//  v3: launch_bounds(256,8) + reg tables -> spill, 90 us.
//  v4: natural regs (68 VGPR) -> 44 us.
//  v5: coalesced chunk layout -> ~41 us.
//  v6: per-use tables, VGPR=28, 61% occupancy -> 42.9 us. Occupancy,
//      coalescing, barriers all falsified as limiters.
//  v7: single-wave no-barrier -> 60-76 us (parallelism collapse).
//  v8: plain stores instead of nontemporal -> <40.8 us (~neutral).
//      NT stores exonerated.
//  v9 (this round): time is invariant to everything EXCEPT the per-row
//      critical chain (load-wait -> scatter -> barrier-drain -> gather ->
//      store), paid once per row with only ~800 issue-cycles of work to
//      amortize it; identical blocks convoy so TLP can't fill the bubbles.
//      So: amortize. TWO rows per block processed CONCURRENTLY, two packet
//      buffers, ONE barrier serving both. 2x MLP in each latency window,
//      half the barriers per row, and all tables (diag_b/g/s, pidx) loaded
//      once per chunk and used for both rows. LDS 32 KB -> 5 blocks/CU.

#define D   4096
#define NT  256            // 4 chunks x 4 columns per thread (per row)
#define R   2              // rows per block, concurrent, one shared barrier

#define C_INV_SQRT2 0.70710678118654752440f

typedef float vf2 __attribute__((ext_vector_type(2)));
typedef float vf4 __attribute__((ext_vector_type(4)));

// One Haar chunk: 4 contiguous columns -> d1 pair, d2, and level-3 value
// (even lane: cA3, odd lane: cD3) via cross-lane pairing of a2.
static __device__ __forceinline__ void haar_chunk(
    float v0, float v1, float v2, float v3, int odd,
    float& d1a, float& d1b, float& d2v, float& l3)
{
    float a10 = (v0 + v1) * C_INV_SQRT2;
    d1a       = (v0 - v1) * C_INV_SQRT2;
    float a11 = (v2 + v3) * C_INV_SQRT2;
    d1b       = (v2 - v3) * C_INV_SQRT2;
    float a2  = (a10 + a11) * C_INV_SQRT2;
    d2v       = (a10 - a11) * C_INV_SQRT2;
    float a2p = __shfl_xor(a2, 1);              // neighbor's a2 (lane t^1)
    // even lane holds a2[2m], partner a2[2m+1]:  a3 = (a2 + a2p)*c
    // odd  lane holds a2[2m+1], partner a2[2m]:  d3 = (a2p - a2)*c
    l3 = (odd ? (a2p - a2) : (a2 + a2p)) * C_INV_SQRT2;
}

__global__ __launch_bounds__(NT, 4) void wavelet_rows_kernel(
    const float* __restrict__ x,
    const float* __restrict__ diag_s,
    const float* __restrict__ diag_g,
    const float* __restrict__ diag_b,
    const int*   __restrict__ perm,
    float*       __restrict__ out)
{
    __shared__ float buf[R][D];       // two packet buffers: 32 KB/block

    const int t   = threadIdx.x;
    const int s   = t >> 1;           // lane-pair index
    const int odd = t & 1;
    const size_t row0 = (size_t)blockIdx.x * R;

    const vf4*  b4 = (const vf4*)diag_b;
    const vf4*  g4 = (const vf4*)diag_g;
    const int4* p4 = (const int4*)perm;
    const vf2*  s2 = (const vf2*)diag_s;

    // ---- phase A: both rows' loads in flight together, DWT #1, scatter ----
    #pragma unroll
    for (int k = 0; k < 4; ++k) {
        vf4 bv = b4[256 * k + t];                      // shared by both rows
        #pragma unroll
        for (int r = 0; r < R; ++r) {
            const vf4* x4 = (const vf4*)(x + (row0 + r) * (size_t)D);
            vf4 xv = x4[256 * k + t];                  // coalesced 16B/lane
            float d1a, d1b, d2v, l3;
            haar_chunk(xv.x * bv.x, xv.y * bv.y,
                       xv.z * bv.z, xv.w * bv.w, odd,
                       d1a, d1b, d2v, l3);
            vf2 dp; dp.x = d1a; dp.y = d1b;
            *(vf2*)&buf[r][2048 + 512 * k + 2 * t] = dp;   // cD1 pair
            buf[r][1024 + 256 * k + t] = d2v;              // cD2
            buf[r][(odd ? 512 : 0) + 128 * k + s] = l3;    // cA3 | cD3
        }
    }

    // prefetch permutation indices; L2 latency overlaps the barrier wait
    int4 pidx[4];
    #pragma unroll
    for (int k = 0; k < 4; ++k) pidx[k] = p4[256 * k + t];

    __syncthreads();                  // ONE barrier for both rows

    // ---- phase B: gather * diag_g, DWT #2, * diag_s, plain store ----
    #pragma unroll
    for (int k = 0; k < 4; ++k) {
        // tables loaded once, used for both rows (L2-hot)
        vf4   gv  = g4[256 * k + t];
        vf2   s1  = s2[1024 + 256 * k + t];            // cD1 scale pair
        float sv2 = diag_s[1024 + 256 * k + t];        // cD2 scale
        float sv3 = diag_s[(odd ? 512 : 0) + 128 * k + s];  // cA3|cD3 scale

        #pragma unroll
        for (int r = 0; r < R; ++r) {
            float w0 = buf[r][pidx[k].x] * gv.x;
            float w1 = buf[r][pidx[k].y] * gv.y;
            float w2 = buf[r][pidx[k].z] * gv.z;
            float w3 = buf[r][pidx[k].w] * gv.w;
            float e1a, e1b, e2v, f3;
            haar_chunk(w0, w1, w2, w3, odd, e1a, e1b, e2v, f3);

            float* orow = out + (row0 + r) * (size_t)D;
            vf2 ep; ep.x = e1a * s1.x; ep.y = e1b * s1.y;
            ((vf2*)orow)[1024 + 256 * k + t] = ep;
            orow[1024 + 256 * k + t] = e2v * sv2;
            orow[(odd ? 512 : 0) + 128 * k + s] = f3 * sv3;
        }
    }
}

extern "C" void kernel_launch(void* const* d_in, const int* in_sizes, int n_in,
                              void* d_out, int out_size, void* d_ws, size_t ws_size,
                              hipStream_t stream) {
    // setup_inputs() order: x, diag_s, diag_g, diag_b, dec_lo, dec_hi, perm, scales
    const float* x      = (const float*)d_in[0];
    const float* diag_s = (const float*)d_in[1];
    const float* diag_g = (const float*)d_in[2];
    const float* diag_b = (const float*)d_in[3];
    const int* perm     = (const int*)d_in[6];
    float* out          = (float*)d_out;

    wavelet_rows_kernel<<<4096 / R, NT, 0, stream>>>(x, diag_s, diag_g, diag_b,
                                                     perm, out);
}